// Round 13
// baseline (852.667 us; speedup 1.0000x reference)
//
#include <hip/hip_runtime.h>
#include <math.h>

#define NN 50000
#define NE 400000
#define NG 256
#define FIN 79
#define DD 400
#define LDK 448      // padded K / row stride for D-sized bf16 activations (7 x 64)
#define LDK1 128     // padded K for layer-1 z (FIN=79 -> 128, 2 x 64)
#define XP 80        // padded x row (bf16)
#define NPAD 512     // padded N for packed weights (4 x 128 N-tiles)
#define BK 64        // GEMM K-step
#define MT64 ((NN + 63) / 64)   // 782 M-tiles of 64 rows
#define BN_EPS_F 1e-5f

#define SCAN_B 256
#define SCAN_NB ((NN + SCAN_B - 1) / SCAN_B)   // 196

typedef unsigned short u16;
typedef unsigned short ushort8 __attribute__((ext_vector_type(8)));
typedef unsigned short ushort4v __attribute__((ext_vector_type(4)));
typedef short short8 __attribute__((ext_vector_type(8)));
typedef float floatx4 __attribute__((ext_vector_type(4)));

__device__ inline u16 f2bf(float f) {
    unsigned int u = __builtin_bit_cast(unsigned int, f);
    u += 0x7fffu + ((u >> 16) & 1u);          // round-to-nearest-even
    return (u16)(u >> 16);
}
__device__ inline float bf2f(u16 s) {
    unsigned int u = ((unsigned int)s) << 16;
    return __builtin_bit_cast(float, u);
}
__device__ inline float fast_tanh(float x) {
    float e = __expf(2.0f * x);
    return 1.0f - 2.0f / (e + 1.0f);
}

// global -> LDS direct copy, 16 B per lane. LDS dest = uniform base + lane*16.
__device__ __forceinline__ void gld_lds16(const u16* g, u16* l) {
    __builtin_amdgcn_global_load_lds(
        (const __attribute__((address_space(1))) unsigned int*)(size_t)(g),
        (__attribute__((address_space(3))) unsigned int*)(unsigned int)(size_t)(l),
        16, 0, 0);
}

// ---------------- per-graph start offsets via binary search ----------------
__global__ void k_gstart(const int* __restrict__ batch, int* __restrict__ gstart) {
    int g = blockIdx.x * blockDim.x + threadIdx.x;
    if (g > NG) return;
    int lo = 0, hi = NN;
    while (lo < hi) {
        int mid = (lo + hi) >> 1;
        if (batch[mid] < g) lo = mid + 1; else hi = mid;
    }
    gstart[g] = lo;
}

// ---------------- CSR build ----------------
__global__ void k_zero_int(int* __restrict__ p, int n) {
    int i = blockIdx.x * blockDim.x + threadIdx.x;
    if (i < n) p[i] = 0;
}
__global__ void k_hist(const int* __restrict__ dst, int* __restrict__ deg) {
    int e = blockIdx.x * blockDim.x + threadIdx.x;
    if (e < NE) atomicAdd(&deg[dst[e]], 1);
}

// 3-phase hierarchical exclusive scan over deg[NN] -> rowptr/cursor
__global__ void k_scan_a(const int* __restrict__ deg, int* __restrict__ bsum) {
    __shared__ int red[SCAN_B];
    int i = blockIdx.x * SCAN_B + threadIdx.x;
    red[threadIdx.x] = (i < NN) ? deg[i] : 0;
    __syncthreads();
    for (int s = SCAN_B / 2; s > 0; s >>= 1) {
        if (threadIdx.x < s) red[threadIdx.x] += red[threadIdx.x + s];
        __syncthreads();
    }
    if (threadIdx.x == 0) bsum[blockIdx.x] = red[0];
}
__global__ void k_scan_b(const int* __restrict__ bsum, int* __restrict__ boff) {
    __shared__ int buf[SCAN_B];
    int t = threadIdx.x;
    int v = (t < SCAN_NB) ? bsum[t] : 0;
    buf[t] = v;
    __syncthreads();
    for (int off = 1; off < SCAN_B; off <<= 1) {
        int add = (t >= off) ? buf[t - off] : 0;
        __syncthreads();
        buf[t] += add;
        __syncthreads();
    }
    if (t < SCAN_NB) boff[t] = buf[t] - v;   // exclusive
}
__global__ void k_scan_c(const int* __restrict__ deg, const int* __restrict__ boff,
                         int* __restrict__ rowptr, int* __restrict__ cursor) {
    __shared__ int buf[SCAN_B];
    int b = blockIdx.x;
    int i = b * SCAN_B + threadIdx.x;
    int v = (i < NN) ? deg[i] : 0;
    buf[threadIdx.x] = v;
    __syncthreads();
    for (int off = 1; off < SCAN_B; off <<= 1) {
        int add = (threadIdx.x >= off) ? buf[threadIdx.x - off] : 0;
        __syncthreads();
        buf[threadIdx.x] += add;
        __syncthreads();
    }
    int excl = boff[b] + buf[threadIdx.x] - v;
    if (i < NN) { rowptr[i] = excl; cursor[i] = excl; }
    if (b == 0 && threadIdx.x == 0) rowptr[NN] = NE;
}

__global__ void k_fill(const int* __restrict__ src, const int* __restrict__ dst,
                       int* __restrict__ cursor, int* __restrict__ eidx) {
    int e = blockIdx.x * blockDim.x + threadIdx.x;
    if (e < NE) {
        int pos = atomicAdd(&cursor[dst[e]], 1);
        eidx[pos] = src[e];
    }
}

// ---------------- merged weight pack: 7 weights in one launch --------------
__global__ __launch_bounds__(256)
void k_packw_all(const float* __restrict__ w0, const float* __restrict__ w1,
                 const float* __restrict__ w2, const float* __restrict__ w3,
                 const float* __restrict__ w4, const float* __restrict__ w5,
                 const float* __restrict__ w6,
                 u16* __restrict__ d0, u16* __restrict__ d1, u16* __restrict__ d2,
                 u16* __restrict__ d3, u16* __restrict__ d4, u16* __restrict__ d5,
                 u16* __restrict__ d6) {
    int which = blockIdx.y;
    const float* W; u16* Wt; int ldk = LDK, K = DD;
    switch (which) {
        case 0: W = w0; Wt = d0; ldk = LDK1; K = FIN; break;
        case 1: W = w1; Wt = d1; break;
        case 2: W = w2; Wt = d2; break;
        case 3: W = w3; Wt = d3; break;
        case 4: W = w4; Wt = d4; break;
        case 5: W = w5; Wt = d5; break;
        default: W = w6; Wt = d6; break;
    }
    int idx = blockIdx.x * 256 + threadIdx.x;
    if (idx >= NPAD * ldk) return;
    int n = idx / ldk, k = idx - n * ldk;
    float v = (n < DD && k < K) ? W[(size_t)k * DD + n] : 0.0f;
    Wt[idx] = f2bf(v);
}

// ---------------- x pack: fp32 [NN][79] -> bf16 [NN][80] ----------------
__global__ __launch_bounds__(256)
void k_packx(const float* __restrict__ x, u16* __restrict__ xb) {
    int idx = blockIdx.x * 256 + threadIdx.x;
    if (idx >= NN * XP) return;
    int n = idx / XP, c = idx - n * XP;
    xb[idx] = (c < FIN) ? f2bf(x[(size_t)n * FIN + c]) : (u16)0;
}

// ---------------- layer-1 aggregation: wave-per-node, bf16 gather ----------------
__global__ __launch_bounds__(256)
void k_agg1(const u16* __restrict__ xb, const int* __restrict__ rowptr,
            const int* __restrict__ eidx, const float* __restrict__ eps,
            u16* __restrict__ z0) {
    int wave = threadIdx.x >> 6, lane = threadIdx.x & 63;
    int n = blockIdx.x * 4 + wave;
    if (lane >= 32) return;
    u16* zr = z0 + (size_t)n * LDK1;
    if (lane >= 20) {                      // zero pad cols 80..127
        ushort4v zz = {0, 0, 0, 0};
        *(ushort4v*)&zr[XP + (lane - 20) * 4] = zz;
        return;
    }
    float s = 1.0f + eps[0];
    int c4 = lane * 4;
    ushort4v v = *(const ushort4v*)&xb[(size_t)n * XP + c4];
    float a[4];
    #pragma unroll
    for (int t = 0; t < 4; ++t) a[t] = s * bf2f(v[t]);
    int e0 = rowptr[n], e1 = rowptr[n + 1];
    int i = e0;
    for (; i + 2 <= e1; i += 2) {
        int s0 = eidx[i], s1 = eidx[i + 1];
        ushort4v v0 = *(const ushort4v*)&xb[(size_t)s0 * XP + c4];
        ushort4v v1 = *(const ushort4v*)&xb[(size_t)s1 * XP + c4];
        #pragma unroll
        for (int t = 0; t < 4; ++t) a[t] += bf2f(v0[t]) + bf2f(v1[t]);
    }
    if (i < e1) {
        int s0 = eidx[i];
        ushort4v v0 = *(const ushort4v*)&xb[(size_t)s0 * XP + c4];
        #pragma unroll
        for (int t = 0; t < 4; ++t) a[t] += bf2f(v0[t]);
    }
    ushort4v o;
    #pragma unroll
    for (int t = 0; t < 4; ++t) o[t] = f2bf(a[t]);
    *(ushort4v*)&zr[c4] = o;
}

// ---------------- D aggregation: wave-per-node, 400 cols, 4-edge unroll ----
__global__ __launch_bounds__(256)
void k_agg(const u16* __restrict__ h, const int* __restrict__ rowptr,
           const int* __restrict__ eidx, const float* __restrict__ eps,
           u16* __restrict__ z) {
    int wave = threadIdx.x >> 6, lane = threadIdx.x & 63;
    int n = blockIdx.x * 4 + wave;
    if (lane >= 50) return;                 // 50*8 = 400 cols; pad cols stay zero
    float s = 1.0f + eps[0];
    int c8 = lane * 8;
    ushort8 v = *(const ushort8*)(h + (size_t)n * LDK + c8);
    float a[8];
    #pragma unroll
    for (int t = 0; t < 8; ++t) a[t] = s * bf2f(v[t]);
    int e0 = rowptr[n], e1 = rowptr[n + 1];
    int i = e0;
    for (; i + 4 <= e1; i += 4) {
        int s0 = eidx[i], s1 = eidx[i + 1], s2 = eidx[i + 2], s3 = eidx[i + 3];
        ushort8 v0 = *(const ushort8*)(h + (size_t)s0 * LDK + c8);
        ushort8 v1 = *(const ushort8*)(h + (size_t)s1 * LDK + c8);
        ushort8 v2 = *(const ushort8*)(h + (size_t)s2 * LDK + c8);
        ushort8 v3 = *(const ushort8*)(h + (size_t)s3 * LDK + c8);
        #pragma unroll
        for (int t = 0; t < 8; ++t)
            a[t] += (bf2f(v0[t]) + bf2f(v1[t])) + (bf2f(v2[t]) + bf2f(v3[t]));
    }
    for (; i < e1; ++i) {
        int s0 = eidx[i];
        ushort8 v0 = *(const ushort8*)(h + (size_t)s0 * LDK + c8);
        #pragma unroll
        for (int t = 0; t < 8; ++t) a[t] += bf2f(v0[t]);
    }
    ushort8 o;
    #pragma unroll
    for (int t = 0; t < 8; ++t) o[t] = f2bf(a[t]);
    *(ushort8*)(z + (size_t)n * LDK + c8) = o;
}

// ---------------- bf16 MFMA GEMM: 64(M) x 128(N) tile (R11 best) -----------
// 4 waves in 2x2: wave-tile 32(M) x 64(N), acc[2][4] = 32 AGPR, LDS 24 KB.
// __launch_bounds__(256,6): LDS fits 6 blocks/CU (6 x 24.6 = 147 KB < 160);
// reg budget 512/6 ~ 85/wave — acc 32 AGPR + ~50 VGPR should fit w/o spill.
// Staging via global_load_lds w=16, LDS chunk XOR swizzle (r&7) symmetric.
// 1D grid XCD swizzle: 4 N-tiles of an M-tile share an XCD (A L2-reuse).
#define CSTR 136     // Cs row stride in u16
__global__ __launch_bounds__(256, 6)
void k_gemm(const u16* __restrict__ A, int lda, int ktiles,
            const u16* __restrict__ Wt,
            const float* __restrict__ bias,
            const float* __restrict__ bng, const float* __restrict__ bnb,
            const float* __restrict__ bnm, const float* __restrict__ bnv,
            u16* __restrict__ Y, int mode)
{
    __shared__ u16 smem[96 * 128];     // 24576 B
    u16* As = smem;                    // 64 x 64
    u16* Bs = smem + 64 * BK;          // 128 x 64
    u16* Cs = smem;                    // 64 x CSTR = 17408 B (after K-loop)

    int id = blockIdx.x;
    int mt = (id >> 5) * 8 + (id & 7);
    int nt = (id & 31) >> 3;
    if (mt >= MT64) return;
    int m0 = mt * 64;
    int n0 = nt * 128;

    int tid = threadIdx.x;
    int wave = tid >> 6, lane = tid & 63;
    int wm = wave & 1, wn = wave >> 1;

    int srow = lane >> 3;      // staging: row within 8-row group
    int sc   = lane & 7;       // staging: chunk this lane fills
    int lm = lane & 15;        // frag row
    int q  = lane >> 4;        // frag k-quarter

    bool nactive = (n0 + wn * 64) < LDK;   // wave has any valid output cols

    floatx4 acc[2][4] = {};

    for (int kt = 0; kt < ktiles; ++kt) {
        int k0 = kt * BK;
        // wave stages 16 rows of A (2 instrs) + 32 rows of B (4 instrs)
        #pragma unroll
        for (int j = 0; j < 2; ++j) {
            int row = wave * 16 + j * 8 + srow;
            int cs = sc ^ (row & 7);
            int gr = m0 + row; gr = gr < NN ? gr : NN - 1;
            gld_lds16(A + (size_t)gr * lda + k0 + (cs << 3),
                      &As[(wave * 16 + j * 8) * BK]);
        }
        #pragma unroll
        for (int j = 0; j < 4; ++j) {
            int row = wave * 32 + j * 8 + srow;
            int cs = sc ^ (row & 7);
            gld_lds16(Wt + (size_t)(n0 + row) * lda + k0 + (cs << 3),
                      &Bs[(wave * 32 + j * 8) * BK]);
        }
        __syncthreads();

        if (nactive) {
            #pragma unroll
            for (int ks = 0; ks < 2; ++ks) {
                short8 af[2], bf[4];
                #pragma unroll
                for (int i = 0; i < 2; ++i) {
                    int r = wm * 32 + i * 16 + lm;
                    int ch = (ks * 4 + q) ^ (r & 7);
                    af[i] = *(const short8*)&As[r * BK + ch * 8];
                }
                #pragma unroll
                for (int j = 0; j < 4; ++j) {
                    int r = wn * 64 + j * 16 + lm;
                    int ch = (ks * 4 + q) ^ (r & 7);
                    bf[j] = *(const short8*)&Bs[r * BK + ch * 8];
                }
                #pragma unroll
                for (int i = 0; i < 2; ++i)
                    #pragma unroll
                    for (int j = 0; j < 4; ++j)
                        acc[i][j] = __builtin_amdgcn_mfma_f32_16x16x32_bf16(af[i], bf[j], acc[i][j], 0, 0, 0);
            }
        }
        __syncthreads();
    }

    // ---- epilogue: activation -> Cs (bf16) -> coalesced global stores ----
    #pragma unroll
    for (int j = 0; j < 4; ++j) {
        int nl = wn * 64 + j * 16 + lm;        // tile-local col (0..127)
        int n  = n0 + nl;
        bool live = n < DD;
        float bias_c = 0.0f, sc2 = 1.0f, sh = 0.0f;
        if (live) {
            bias_c = bias[n];
            if (mode == 0) {
                sc2 = bng[n] * rsqrtf(bnv[n] + BN_EPS_F);
                sh = bnb[n] - bnm[n] * sc2;
            }
        }
        #pragma unroll
        for (int i = 0; i < 2; ++i) {
            int rl = wm * 32 + i * 16 + q * 4; // tile-local row base (0..63)
            #pragma unroll
            for (int r = 0; r < 4; ++r) {
                u16 o = 0;
                if (live) {
                    float val = acc[i][j][r] + bias_c;
                    if (mode == 0)      val = fmaxf(fmaf(val, sc2, sh), 0.0f);
                    else if (mode == 1) val = fmaxf(val, 0.0f);
                    else                val = fast_tanh(val);
                    o = f2bf(val);
                }
                if (nactive) Cs[(rl + r) * CSTR + nl] = o;
            }
        }
    }
    __syncthreads();

    // 64 rows x 16 chunks of 8 cols: 1024 chunks / 256 threads = 4 each
    int row = tid >> 2, part = tid & 3;
    int m = m0 + row;
    if (m < NN) {
        #pragma unroll
        for (int k = 0; k < 4; ++k) {
            int coloff = part * 32 + k * 8;
            int n = n0 + coloff;
            if (n < LDK) {
                ushort8 v = *(const ushort8*)&Cs[row * CSTR + coloff];
                *(ushort8*)&Y[(size_t)m * LDK + n] = v;
            }
        }
    }
}

// ---------------- pooling: block-per-graph, coalesced rows ----------------
__global__ __launch_bounds__(256)
void k_pool(const u16* __restrict__ t3, const int* __restrict__ gstart,
            float* __restrict__ pooled) {
    __shared__ float smax[4][408];
    __shared__ float ssum[4][408];
    int g = blockIdx.x;
    int wave = threadIdx.x >> 6, lane = threadIdx.x & 63;
    int s = gstart[g], e = gstart[g + 1];
    if (lane < 50) {
        int c8 = lane * 8;
        float mx[8], sm[8];
        #pragma unroll
        for (int t = 0; t < 8; ++t) { mx[t] = -INFINITY; sm[t] = 0.0f; }
        for (int n = s + wave; n < e; n += 4) {
            ushort8 v = *(const ushort8*)&t3[(size_t)n * LDK + c8];
            #pragma unroll
            for (int t = 0; t < 8; ++t) {
                float f = bf2f(v[t]);
                mx[t] = fmaxf(mx[t], f);
                sm[t] += f;
            }
        }
        #pragma unroll
        for (int t = 0; t < 8; ++t) {
            smax[wave][c8 + t] = mx[t];
            ssum[wave][c8 + t] = sm[t];
        }
    }
    __syncthreads();
    float cnt = fmaxf((float)(e - s), 1.0f);
    for (int c = threadIdx.x; c < DD; c += 256) {
        float m = fmaxf(fmaxf(smax[0][c], smax[1][c]), fmaxf(smax[2][c], smax[3][c]));
        float su = ssum[0][c] + ssum[1][c] + ssum[2][c] + ssum[3][c];
        pooled[(size_t)g * 2 * DD + c] = m;
        pooled[(size_t)g * 2 * DD + DD + c] = su / cnt;
    }
}

// ---------------- final readout ----------------
__global__ void k_final(const float* __restrict__ pooled, const float* __restrict__ w,
                        const float* __restrict__ b, float* __restrict__ out) {
    __shared__ float red[256];
    int g = blockIdx.x;
    float p = 0.0f;
    for (int j = threadIdx.x; j < 2 * DD; j += blockDim.x)
        p += pooled[(size_t)g * 2 * DD + j] * w[j];
    red[threadIdx.x] = p;
    __syncthreads();
    for (int s = 128; s > 0; s >>= 1) {
        if (threadIdx.x < s) red[threadIdx.x] += red[threadIdx.x + s];
        __syncthreads();
    }
    if (threadIdx.x == 0) out[g] = red[0] + b[0];
}

extern "C" void kernel_launch(void* const* d_in, const int* in_sizes, int n_in,
                              void* d_out, int out_size, void* d_ws, size_t ws_size,
                              hipStream_t stream) {
    const float* x     = (const float*)d_in[0];
    const int*   ei    = (const int*)d_in[1];
    const int*   batch = (const int*)d_in[2];
    const float* m1w1  = (const float*)d_in[4];
    const float* m1b1  = (const float*)d_in[5];
    const float* m1g   = (const float*)d_in[6];
    const float* m1bb  = (const float*)d_in[7];
    const float* m1m   = (const float*)d_in[8];
    const float* m1v   = (const float*)d_in[9];
    const float* m1w2  = (const float*)d_in[10];
    const float* m1b2  = (const float*)d_in[11];
    const float* m2w1  = (const float*)d_in[12];
    const float* m2b1  = (const float*)d_in[13];
    const float* m2g   = (const float*)d_in[14];
    const float* m2bb  = (const float*)d_in[15];
    const float* m2m   = (const float*)d_in[16];
    const float* m2v   = (const float*)d_in[17];
    const float* m2w2  = (const float*)d_in[18];
    const float* m2b2  = (const float*)d_in[19];
    const float* o1w   = (const float*)d_in[20];
    const float* o1b   = (const float*)d_in[21];
    const float* o2w   = (const float*)d_in[22];
    const float* o2b   = (const float*)d_in[23];
    const float* o3w   = (const float*)d_in[24];
    const float* o3b   = (const float*)d_in[25];
    const float* ow    = (const float*)d_in[26];
    const float* ob    = (const float*)d_in[27];
    const float* eps1  = (const float*)d_in[28];
    const float* eps2  = (const float*)d_in[29];
    const float* eps3  = (const float*)d_in[30];
    const int* srcI = ei;
    const int* dstI = ei + NE;

    // ---- workspace layout (all 16B-aligned chunks) ----
    u16* buf1 = (u16*)d_ws;                          // NN*LDK
    u16* buf2 = buf1 + (size_t)NN * LDK;
    u16* buf3 = buf2 + (size_t)NN * LDK;
    u16* z0   = buf3 + (size_t)NN * LDK;             // NN*LDK1
    u16* w1t  = z0 + (size_t)NN * LDK1;              // NPAD*LDK1
    u16* m1w2t = w1t + (size_t)NPAD * LDK1;          // NPAD*LDK each
    u16* m2w1t = m1w2t + (size_t)NPAD * LDK;
    u16* m2w2t = m2w1t + (size_t)NPAD * LDK;
    u16* o1t   = m2w2t + (size_t)NPAD * LDK;
    u16* o2t   = o1t + (size_t)NPAD * LDK;
    u16* o3t   = o2t + (size_t)NPAD * LDK;
    u16* xb    = o3t + (size_t)NPAD * LDK;                // NN*XP
    float* pooled = (float*)(xb + (size_t)NN * XP);       // NG*2*DD
    int* gstart = (int*)(pooled + (size_t)NG * 2 * DD);   // NG+1
    int* rowptr = gstart + (NG + 2);                      // NN+1
    int* cursor = rowptr + (NN + 1);                      // NN
    int* deg    = cursor + NN;                            // NN
    int* eidx   = deg + NN;                               // NE
    int* bsum   = eidx + NE;                              // SCAN_NB
    int* boff   = bsum + SCAN_NB;                         // SCAN_NB

    float* out = (float*)d_out;

    // 1D swizzled GEMM grid: groups of 32 ids = 8 M-tiles x 4 N-tiles
    int gemmBlocks = ((MT64 + 7) / 8) * 32;   // 98*32 = 3136

    // graph structure (same every call)
    k_gstart<<<2, 256, 0, stream>>>(batch, gstart);
    k_zero_int<<<(NN + 255) / 256, 256, 0, stream>>>(deg, NN);
    k_hist<<<(NE + 255) / 256, 256, 0, stream>>>(dstI, deg);
    k_scan_a<<<SCAN_NB, SCAN_B, 0, stream>>>(deg, bsum);
    k_scan_b<<<1, SCAN_B, 0, stream>>>(bsum, boff);
    k_scan_c<<<SCAN_NB, SCAN_B, 0, stream>>>(deg, boff, rowptr, cursor);
    k_fill<<<(NE + 255) / 256, 256, 0, stream>>>(srcI, dstI, cursor, eidx);

    // pack weights (one launch) + x to bf16
    dim3 pwGrid((NPAD * LDK + 255) / 256, 7);
    k_packw_all<<<pwGrid, 256, 0, stream>>>(m1w1, m1w2, m2w1, m2w2, o1w, o2w, o3w,
                                            w1t, m1w2t, m2w1t, m2w2t, o1t, o2t, o3t);
    k_packx<<<(NN * XP + 255) / 256, 256, 0, stream>>>(x, xb);

    // ---- layer 1 ----
    k_agg1<<<NN / 4, 256, 0, stream>>>(xb, rowptr, eidx, eps1, z0);
    k_gemm<<<gemmBlocks, 256, 0, stream>>>(z0, LDK1, LDK1 / BK, w1t, m1b1,
                                           m1g, m1bb, m1m, m1v, buf1, 0);
    k_gemm<<<gemmBlocks, 256, 0, stream>>>(buf1, LDK, LDK / BK, m1w2t, m1b2,
                                           nullptr, nullptr, nullptr, nullptr, buf2, 1);
    k_gemm<<<gemmBlocks, 256, 0, stream>>>(buf2, LDK, LDK / BK, o1t, o1b,
                                           nullptr, nullptr, nullptr, nullptr, buf3, 2);  // t1 = buf3

    // ---- layer 2 ----
    k_agg<<<NN / 4, 256, 0, stream>>>(buf3, rowptr, eidx, eps2, buf1);
    k_gemm<<<gemmBlocks, 256, 0, stream>>>(buf1, LDK, LDK / BK, m2w1t, m2b1,
                                           m2g, m2bb, m2m, m2v, buf2, 0);
    k_gemm<<<gemmBlocks, 256, 0, stream>>>(buf2, LDK, LDK / BK, m2w2t, m2b2,
                                           nullptr, nullptr, nullptr, nullptr, buf1, 1);
    k_gemm<<<gemmBlocks, 256, 0, stream>>>(buf1, LDK, LDK / BK, o2t, o2b,
                                           nullptr, nullptr, nullptr, nullptr, buf2, 2);  // t2 = buf2

    // ---- layer 3 (mlp2 weights again) ----
    k_agg<<<NN / 4, 256, 0, stream>>>(buf2, rowptr, eidx, eps3, buf1);
    k_gemm<<<gemmBlocks, 256, 0, stream>>>(buf1, LDK, LDK / BK, m2w1t, m2b1,
                                           m2g, m2bb, m2m, m2v, buf3, 0);
    k_gemm<<<gemmBlocks, 256, 0, stream>>>(buf3, LDK, LDK / BK, m2w2t, m2b2,
                                           nullptr, nullptr, nullptr, nullptr, buf1, 1);
    k_gemm<<<gemmBlocks, 256, 0, stream>>>(buf1, LDK, LDK / BK, o3t, o3b,
                                           nullptr, nullptr, nullptr, nullptr, buf3, 2);  // t3 = buf3

    // ---- pooling + readout ----
    k_pool<<<NG, 256, 0, stream>>>(buf3, gstart, pooled);
    k_final<<<NG, 256, 0, stream>>>(pooled, ow, ob, out);
}

// Round 14
// 738.989 us; speedup vs baseline: 1.1538x; 1.1538x over previous
//
#include <hip/hip_runtime.h>
#include <math.h>

#define NN 50000
#define NE 400000
#define NG 256
#define FIN 79
#define DD 400
#define LDK 448      // padded K / row stride for D-sized bf16 activations (7 x 64)
#define LDK1 128     // padded K for layer-1 z (FIN=79 -> 128, 2 x 64)
#define XP 80        // padded x row (bf16)
#define NPAD 512     // padded N for packed weights (4 x 128 N-tiles)
#define BK 64        // GEMM K-step
#define MT64 ((NN + 63) / 64)   // 782 M-tiles of 64 rows
#define BN_EPS_F 1e-5f

#define SCAN_B 256
#define SCAN_NB ((NN + SCAN_B - 1) / SCAN_B)   // 196

typedef unsigned short u16;
typedef unsigned short ushort8 __attribute__((ext_vector_type(8)));
typedef unsigned short ushort4v __attribute__((ext_vector_type(4)));
typedef short short8 __attribute__((ext_vector_type(8)));
typedef float floatx4 __attribute__((ext_vector_type(4)));

__device__ inline u16 f2bf(float f) {
    unsigned int u = __builtin_bit_cast(unsigned int, f);
    u += 0x7fffu + ((u >> 16) & 1u);          // round-to-nearest-even
    return (u16)(u >> 16);
}
__device__ inline float bf2f(u16 s) {
    unsigned int u = ((unsigned int)s) << 16;
    return __builtin_bit_cast(float, u);
}
__device__ inline float fast_tanh(float x) {
    float e = __expf(2.0f * x);
    return 1.0f - 2.0f / (e + 1.0f);
}

// global -> LDS direct copy, 16 B per lane. LDS dest = uniform base + lane*16.
__device__ __forceinline__ void gld_lds16(const u16* g, u16* l) {
    __builtin_amdgcn_global_load_lds(
        (const __attribute__((address_space(1))) unsigned int*)(size_t)(g),
        (__attribute__((address_space(3))) unsigned int*)(unsigned int)(size_t)(l),
        16, 0, 0);
}

// ---------------- per-graph start offsets via binary search ----------------
__global__ void k_gstart(const int* __restrict__ batch, int* __restrict__ gstart) {
    int g = blockIdx.x * blockDim.x + threadIdx.x;
    if (g > NG) return;
    int lo = 0, hi = NN;
    while (lo < hi) {
        int mid = (lo + hi) >> 1;
        if (batch[mid] < g) lo = mid + 1; else hi = mid;
    }
    gstart[g] = lo;
}

// ---------------- CSR build ----------------
__global__ void k_zero_int(int* __restrict__ p, int n) {
    int i = blockIdx.x * blockDim.x + threadIdx.x;
    if (i < n) p[i] = 0;
}
__global__ void k_hist(const int* __restrict__ dst, int* __restrict__ deg) {
    int e = blockIdx.x * blockDim.x + threadIdx.x;
    if (e < NE) atomicAdd(&deg[dst[e]], 1);
}

// 3-phase hierarchical exclusive scan over deg[NN] -> rowptr/cursor
__global__ void k_scan_a(const int* __restrict__ deg, int* __restrict__ bsum) {
    __shared__ int red[SCAN_B];
    int i = blockIdx.x * SCAN_B + threadIdx.x;
    red[threadIdx.x] = (i < NN) ? deg[i] : 0;
    __syncthreads();
    for (int s = SCAN_B / 2; s > 0; s >>= 1) {
        if (threadIdx.x < s) red[threadIdx.x] += red[threadIdx.x + s];
        __syncthreads();
    }
    if (threadIdx.x == 0) bsum[blockIdx.x] = red[0];
}
__global__ void k_scan_b(const int* __restrict__ bsum, int* __restrict__ boff) {
    __shared__ int buf[SCAN_B];
    int t = threadIdx.x;
    int v = (t < SCAN_NB) ? bsum[t] : 0;
    buf[t] = v;
    __syncthreads();
    for (int off = 1; off < SCAN_B; off <<= 1) {
        int add = (t >= off) ? buf[t - off] : 0;
        __syncthreads();
        buf[t] += add;
        __syncthreads();
    }
    if (t < SCAN_NB) boff[t] = buf[t] - v;   // exclusive
}
__global__ void k_scan_c(const int* __restrict__ deg, const int* __restrict__ boff,
                         int* __restrict__ rowptr, int* __restrict__ cursor) {
    __shared__ int buf[SCAN_B];
    int b = blockIdx.x;
    int i = b * SCAN_B + threadIdx.x;
    int v = (i < NN) ? deg[i] : 0;
    buf[threadIdx.x] = v;
    __syncthreads();
    for (int off = 1; off < SCAN_B; off <<= 1) {
        int add = (threadIdx.x >= off) ? buf[threadIdx.x - off] : 0;
        __syncthreads();
        buf[threadIdx.x] += add;
        __syncthreads();
    }
    int excl = boff[b] + buf[threadIdx.x] - v;
    if (i < NN) { rowptr[i] = excl; cursor[i] = excl; }
    if (b == 0 && threadIdx.x == 0) rowptr[NN] = NE;
}

__global__ void k_fill(const int* __restrict__ src, const int* __restrict__ dst,
                       int* __restrict__ cursor, int* __restrict__ eidx) {
    int e = blockIdx.x * blockDim.x + threadIdx.x;
    if (e < NE) {
        int pos = atomicAdd(&cursor[dst[e]], 1);
        eidx[pos] = src[e];
    }
}

// ---------------- merged weight pack: 7 weights in one launch --------------
__global__ __launch_bounds__(256)
void k_packw_all(const float* __restrict__ w0, const float* __restrict__ w1,
                 const float* __restrict__ w2, const float* __restrict__ w3,
                 const float* __restrict__ w4, const float* __restrict__ w5,
                 const float* __restrict__ w6,
                 u16* __restrict__ d0, u16* __restrict__ d1, u16* __restrict__ d2,
                 u16* __restrict__ d3, u16* __restrict__ d4, u16* __restrict__ d5,
                 u16* __restrict__ d6) {
    int which = blockIdx.y;
    const float* W; u16* Wt; int ldk = LDK, K = DD;
    switch (which) {
        case 0: W = w0; Wt = d0; ldk = LDK1; K = FIN; break;
        case 1: W = w1; Wt = d1; break;
        case 2: W = w2; Wt = d2; break;
        case 3: W = w3; Wt = d3; break;
        case 4: W = w4; Wt = d4; break;
        case 5: W = w5; Wt = d5; break;
        default: W = w6; Wt = d6; break;
    }
    int idx = blockIdx.x * 256 + threadIdx.x;
    if (idx >= NPAD * ldk) return;
    int n = idx / ldk, k = idx - n * ldk;
    float v = (n < DD && k < K) ? W[(size_t)k * DD + n] : 0.0f;
    Wt[idx] = f2bf(v);
}

// ---------------- x pack: fp32 [NN][79] -> bf16 [NN][80] ----------------
__global__ __launch_bounds__(256)
void k_packx(const float* __restrict__ x, u16* __restrict__ xb) {
    int idx = blockIdx.x * 256 + threadIdx.x;
    if (idx >= NN * XP) return;
    int n = idx / XP, c = idx - n * XP;
    xb[idx] = (c < FIN) ? f2bf(x[(size_t)n * FIN + c]) : (u16)0;
}

// ---------------- layer-1 aggregation: wave-per-node, bf16 gather ----------------
__global__ __launch_bounds__(256)
void k_agg1(const u16* __restrict__ xb, const int* __restrict__ rowptr,
            const int* __restrict__ eidx, const float* __restrict__ eps,
            u16* __restrict__ z0) {
    int wave = threadIdx.x >> 6, lane = threadIdx.x & 63;
    int n = blockIdx.x * 4 + wave;
    if (lane >= 32) return;
    u16* zr = z0 + (size_t)n * LDK1;
    if (lane >= 20) {                      // zero pad cols 80..127
        ushort4v zz = {0, 0, 0, 0};
        *(ushort4v*)&zr[XP + (lane - 20) * 4] = zz;
        return;
    }
    float s = 1.0f + eps[0];
    int c4 = lane * 4;
    ushort4v v = *(const ushort4v*)&xb[(size_t)n * XP + c4];
    float a[4];
    #pragma unroll
    for (int t = 0; t < 4; ++t) a[t] = s * bf2f(v[t]);
    int e0 = rowptr[n], e1 = rowptr[n + 1];
    int i = e0;
    for (; i + 2 <= e1; i += 2) {
        int s0 = eidx[i], s1 = eidx[i + 1];
        ushort4v v0 = *(const ushort4v*)&xb[(size_t)s0 * XP + c4];
        ushort4v v1 = *(const ushort4v*)&xb[(size_t)s1 * XP + c4];
        #pragma unroll
        for (int t = 0; t < 4; ++t) a[t] += bf2f(v0[t]) + bf2f(v1[t]);
    }
    if (i < e1) {
        int s0 = eidx[i];
        ushort4v v0 = *(const ushort4v*)&xb[(size_t)s0 * XP + c4];
        #pragma unroll
        for (int t = 0; t < 4; ++t) a[t] += bf2f(v0[t]);
    }
    ushort4v o;
    #pragma unroll
    for (int t = 0; t < 4; ++t) o[t] = f2bf(a[t]);
    *(ushort4v*)&zr[c4] = o;
}

// ---------------- D aggregation: wave-per-node, 400 cols, 4-edge unroll ----
__global__ __launch_bounds__(256)
void k_agg(const u16* __restrict__ h, const int* __restrict__ rowptr,
           const int* __restrict__ eidx, const float* __restrict__ eps,
           u16* __restrict__ z) {
    int wave = threadIdx.x >> 6, lane = threadIdx.x & 63;
    int n = blockIdx.x * 4 + wave;
    if (lane >= 50) return;                 // 50*8 = 400 cols; pad cols stay zero
    float s = 1.0f + eps[0];
    int c8 = lane * 8;
    ushort8 v = *(const ushort8*)(h + (size_t)n * LDK + c8);
    float a[8];
    #pragma unroll
    for (int t = 0; t < 8; ++t) a[t] = s * bf2f(v[t]);
    int e0 = rowptr[n], e1 = rowptr[n + 1];
    int i = e0;
    for (; i + 4 <= e1; i += 4) {
        int s0 = eidx[i], s1 = eidx[i + 1], s2 = eidx[i + 2], s3 = eidx[i + 3];
        ushort8 v0 = *(const ushort8*)(h + (size_t)s0 * LDK + c8);
        ushort8 v1 = *(const ushort8*)(h + (size_t)s1 * LDK + c8);
        ushort8 v2 = *(const ushort8*)(h + (size_t)s2 * LDK + c8);
        ushort8 v3 = *(const ushort8*)(h + (size_t)s3 * LDK + c8);
        #pragma unroll
        for (int t = 0; t < 8; ++t)
            a[t] += (bf2f(v0[t]) + bf2f(v1[t])) + (bf2f(v2[t]) + bf2f(v3[t]));
    }
    for (; i < e1; ++i) {
        int s0 = eidx[i];
        ushort8 v0 = *(const ushort8*)(h + (size_t)s0 * LDK + c8);
        #pragma unroll
        for (int t = 0; t < 8; ++t) a[t] += bf2f(v0[t]);
    }
    ushort8 o;
    #pragma unroll
    for (int t = 0; t < 8; ++t) o[t] = f2bf(a[t]);
    *(ushort8*)(z + (size_t)n * LDK + c8) = o;
}

// ---------------- bf16 MFMA GEMM: 64(M) x 128(N) tile (R11 best, restored) --
// 4 waves in 2x2: wave-tile 32(M) x 64(N), acc[2][4] = 32 AGPR, ~90 unified
// regs, LDS 24 KB -> 5 blocks/CU (20 waves). LB(256,5) is the measured
// optimum: LB(256,6) squeezes VGPRs to 40 and regresses (R13: 47 -> 66 us).
// Staging via global_load_lds w=16, LDS chunk XOR swizzle (r&7) symmetric.
// 1D grid XCD swizzle: 4 N-tiles of an M-tile share an XCD (A L2-reuse).
#define CSTR 136     // Cs row stride in u16
__global__ __launch_bounds__(256, 5)
void k_gemm(const u16* __restrict__ A, int lda, int ktiles,
            const u16* __restrict__ Wt,
            const float* __restrict__ bias,
            const float* __restrict__ bng, const float* __restrict__ bnb,
            const float* __restrict__ bnm, const float* __restrict__ bnv,
            u16* __restrict__ Y, int mode)
{
    __shared__ u16 smem[96 * 128];     // 24576 B
    u16* As = smem;                    // 64 x 64
    u16* Bs = smem + 64 * BK;          // 128 x 64
    u16* Cs = smem;                    // 64 x CSTR = 17408 B (after K-loop)

    int id = blockIdx.x;
    int mt = (id >> 5) * 8 + (id & 7);
    int nt = (id & 31) >> 3;
    if (mt >= MT64) return;
    int m0 = mt * 64;
    int n0 = nt * 128;

    int tid = threadIdx.x;
    int wave = tid >> 6, lane = tid & 63;
    int wm = wave & 1, wn = wave >> 1;

    int srow = lane >> 3;      // staging: row within 8-row group
    int sc   = lane & 7;       // staging: chunk this lane fills
    int lm = lane & 15;        // frag row
    int q  = lane >> 4;        // frag k-quarter

    bool nactive = (n0 + wn * 64) < LDK;   // wave has any valid output cols

    floatx4 acc[2][4] = {};

    for (int kt = 0; kt < ktiles; ++kt) {
        int k0 = kt * BK;
        // wave stages 16 rows of A (2 instrs) + 32 rows of B (4 instrs)
        #pragma unroll
        for (int j = 0; j < 2; ++j) {
            int row = wave * 16 + j * 8 + srow;
            int cs = sc ^ (row & 7);
            int gr = m0 + row; gr = gr < NN ? gr : NN - 1;
            gld_lds16(A + (size_t)gr * lda + k0 + (cs << 3),
                      &As[(wave * 16 + j * 8) * BK]);
        }
        #pragma unroll
        for (int j = 0; j < 4; ++j) {
            int row = wave * 32 + j * 8 + srow;
            int cs = sc ^ (row & 7);
            gld_lds16(Wt + (size_t)(n0 + row) * lda + k0 + (cs << 3),
                      &Bs[(wave * 32 + j * 8) * BK]);
        }
        __syncthreads();

        if (nactive) {
            #pragma unroll
            for (int ks = 0; ks < 2; ++ks) {
                short8 af[2], bf[4];
                #pragma unroll
                for (int i = 0; i < 2; ++i) {
                    int r = wm * 32 + i * 16 + lm;
                    int ch = (ks * 4 + q) ^ (r & 7);
                    af[i] = *(const short8*)&As[r * BK + ch * 8];
                }
                #pragma unroll
                for (int j = 0; j < 4; ++j) {
                    int r = wn * 64 + j * 16 + lm;
                    int ch = (ks * 4 + q) ^ (r & 7);
                    bf[j] = *(const short8*)&Bs[r * BK + ch * 8];
                }
                #pragma unroll
                for (int i = 0; i < 2; ++i)
                    #pragma unroll
                    for (int j = 0; j < 4; ++j)
                        acc[i][j] = __builtin_amdgcn_mfma_f32_16x16x32_bf16(af[i], bf[j], acc[i][j], 0, 0, 0);
            }
        }
        __syncthreads();
    }

    // ---- epilogue: activation -> Cs (bf16) -> coalesced global stores ----
    #pragma unroll
    for (int j = 0; j < 4; ++j) {
        int nl = wn * 64 + j * 16 + lm;        // tile-local col (0..127)
        int n  = n0 + nl;
        bool live = n < DD;
        float bias_c = 0.0f, sc2 = 1.0f, sh = 0.0f;
        if (live) {
            bias_c = bias[n];
            if (mode == 0) {
                sc2 = bng[n] * rsqrtf(bnv[n] + BN_EPS_F);
                sh = bnb[n] - bnm[n] * sc2;
            }
        }
        #pragma unroll
        for (int i = 0; i < 2; ++i) {
            int rl = wm * 32 + i * 16 + q * 4; // tile-local row base (0..63)
            #pragma unroll
            for (int r = 0; r < 4; ++r) {
                u16 o = 0;
                if (live) {
                    float val = acc[i][j][r] + bias_c;
                    if (mode == 0)      val = fmaxf(fmaf(val, sc2, sh), 0.0f);
                    else if (mode == 1) val = fmaxf(val, 0.0f);
                    else                val = fast_tanh(val);
                    o = f2bf(val);
                }
                if (nactive) Cs[(rl + r) * CSTR + nl] = o;
            }
        }
    }
    __syncthreads();

    // 64 rows x 16 chunks of 8 cols: 1024 chunks / 256 threads = 4 each
    int row = tid >> 2, part = tid & 3;
    int m = m0 + row;
    if (m < NN) {
        #pragma unroll
        for (int k = 0; k < 4; ++k) {
            int coloff = part * 32 + k * 8;
            int n = n0 + coloff;
            if (n < LDK) {
                ushort8 v = *(const ushort8*)&Cs[row * CSTR + coloff];
                *(ushort8*)&Y[(size_t)m * LDK + n] = v;
            }
        }
    }
}

// ---------------- pooling: block-per-graph, coalesced rows ----------------
__global__ __launch_bounds__(256)
void k_pool(const u16* __restrict__ t3, const int* __restrict__ gstart,
            float* __restrict__ pooled) {
    __shared__ float smax[4][408];
    __shared__ float ssum[4][408];
    int g = blockIdx.x;
    int wave = threadIdx.x >> 6, lane = threadIdx.x & 63;
    int s = gstart[g], e = gstart[g + 1];
    if (lane < 50) {
        int c8 = lane * 8;
        float mx[8], sm[8];
        #pragma unroll
        for (int t = 0; t < 8; ++t) { mx[t] = -INFINITY; sm[t] = 0.0f; }
        for (int n = s + wave; n < e; n += 4) {
            ushort8 v = *(const ushort8*)&t3[(size_t)n * LDK + c8];
            #pragma unroll
            for (int t = 0; t < 8; ++t) {
                float f = bf2f(v[t]);
                mx[t] = fmaxf(mx[t], f);
                sm[t] += f;
            }
        }
        #pragma unroll
        for (int t = 0; t < 8; ++t) {
            smax[wave][c8 + t] = mx[t];
            ssum[wave][c8 + t] = sm[t];
        }
    }
    __syncthreads();
    float cnt = fmaxf((float)(e - s), 1.0f);
    for (int c = threadIdx.x; c < DD; c += 256) {
        float m = fmaxf(fmaxf(smax[0][c], smax[1][c]), fmaxf(smax[2][c], smax[3][c]));
        float su = ssum[0][c] + ssum[1][c] + ssum[2][c] + ssum[3][c];
        pooled[(size_t)g * 2 * DD + c] = m;
        pooled[(size_t)g * 2 * DD + DD + c] = su / cnt;
    }
}

// ---------------- final readout ----------------
__global__ void k_final(const float* __restrict__ pooled, const float* __restrict__ w,
                        const float* __restrict__ b, float* __restrict__ out) {
    __shared__ float red[256];
    int g = blockIdx.x;
    float p = 0.0f;
    for (int j = threadIdx.x; j < 2 * DD; j += blockDim.x)
        p += pooled[(size_t)g * 2 * DD + j] * w[j];
    red[threadIdx.x] = p;
    __syncthreads();
    for (int s = 128; s > 0; s >>= 1) {
        if (threadIdx.x < s) red[threadIdx.x] += red[threadIdx.x + s];
        __syncthreads();
    }
    if (threadIdx.x == 0) out[g] = red[0] + b[0];
}

extern "C" void kernel_launch(void* const* d_in, const int* in_sizes, int n_in,
                              void* d_out, int out_size, void* d_ws, size_t ws_size,
                              hipStream_t stream) {
    const float* x     = (const float*)d_in[0];
    const int*   ei    = (const int*)d_in[1];
    const int*   batch = (const int*)d_in[2];
    const float* m1w1  = (const float*)d_in[4];
    const float* m1b1  = (const float*)d_in[5];
    const float* m1g   = (const float*)d_in[6];
    const float* m1bb  = (const float*)d_in[7];
    const float* m1m   = (const float*)d_in[8];
    const float* m1v   = (const float*)d_in[9];
    const float* m1w2  = (const float*)d_in[10];
    const float* m1b2  = (const float*)d_in[11];
    const float* m2w1  = (const float*)d_in[12];
    const float* m2b1  = (const float*)d_in[13];
    const float* m2g   = (const float*)d_in[14];
    const float* m2bb  = (const float*)d_in[15];
    const float* m2m   = (const float*)d_in[16];
    const float* m2v   = (const float*)d_in[17];
    const float* m2w2  = (const float*)d_in[18];
    const float* m2b2  = (const float*)d_in[19];
    const float* o1w   = (const float*)d_in[20];
    const float* o1b   = (const float*)d_in[21];
    const float* o2w   = (const float*)d_in[22];
    const float* o2b   = (const float*)d_in[23];
    const float* o3w   = (const float*)d_in[24];
    const float* o3b   = (const float*)d_in[25];
    const float* ow    = (const float*)d_in[26];
    const float* ob    = (const float*)d_in[27];
    const float* eps1  = (const float*)d_in[28];
    const float* eps2  = (const float*)d_in[29];
    const float* eps3  = (const float*)d_in[30];
    const int* srcI = ei;
    const int* dstI = ei + NE;

    // ---- workspace layout (all 16B-aligned chunks) ----
    u16* buf1 = (u16*)d_ws;                          // NN*LDK
    u16* buf2 = buf1 + (size_t)NN * LDK;
    u16* buf3 = buf2 + (size_t)NN * LDK;
    u16* z0   = buf3 + (size_t)NN * LDK;             // NN*LDK1
    u16* w1t  = z0 + (size_t)NN * LDK1;              // NPAD*LDK1
    u16* m1w2t = w1t + (size_t)NPAD * LDK1;          // NPAD*LDK each
    u16* m2w1t = m1w2t + (size_t)NPAD * LDK;
    u16* m2w2t = m2w1t + (size_t)NPAD * LDK;
    u16* o1t   = m2w2t + (size_t)NPAD * LDK;
    u16* o2t   = o1t + (size_t)NPAD * LDK;
    u16* o3t   = o2t + (size_t)NPAD * LDK;
    u16* xb    = o3t + (size_t)NPAD * LDK;                // NN*XP
    float* pooled = (float*)(xb + (size_t)NN * XP);       // NG*2*DD
    int* gstart = (int*)(pooled + (size_t)NG * 2 * DD);   // NG+1
    int* rowptr = gstart + (NG + 2);                      // NN+1
    int* cursor = rowptr + (NN + 1);                      // NN
    int* deg    = cursor + NN;                            // NN
    int* eidx   = deg + NN;                               // NE
    int* bsum   = eidx + NE;                              // SCAN_NB
    int* boff   = bsum + SCAN_NB;                         // SCAN_NB

    float* out = (float*)d_out;

    // 1D swizzled GEMM grid: groups of 32 ids = 8 M-tiles x 4 N-tiles
    int gemmBlocks = ((MT64 + 7) / 8) * 32;   // 98*32 = 3136

    // graph structure (same every call)
    k_gstart<<<2, 256, 0, stream>>>(batch, gstart);
    k_zero_int<<<(NN + 255) / 256, 256, 0, stream>>>(deg, NN);
    k_hist<<<(NE + 255) / 256, 256, 0, stream>>>(dstI, deg);
    k_scan_a<<<SCAN_NB, SCAN_B, 0, stream>>>(deg, bsum);
    k_scan_b<<<1, SCAN_B, 0, stream>>>(bsum, boff);
    k_scan_c<<<SCAN_NB, SCAN_B, 0, stream>>>(deg, boff, rowptr, cursor);
    k_fill<<<(NE + 255) / 256, 256, 0, stream>>>(srcI, dstI, cursor, eidx);

    // pack weights (one launch) + x to bf16
    dim3 pwGrid((NPAD * LDK + 255) / 256, 7);
    k_packw_all<<<pwGrid, 256, 0, stream>>>(m1w1, m1w2, m2w1, m2w2, o1w, o2w, o3w,
                                            w1t, m1w2t, m2w1t, m2w2t, o1t, o2t, o3t);
    k_packx<<<(NN * XP + 255) / 256, 256, 0, stream>>>(x, xb);

    // ---- layer 1 ----
    k_agg1<<<NN / 4, 256, 0, stream>>>(xb, rowptr, eidx, eps1, z0);
    k_gemm<<<gemmBlocks, 256, 0, stream>>>(z0, LDK1, LDK1 / BK, w1t, m1b1,
                                           m1g, m1bb, m1m, m1v, buf1, 0);
    k_gemm<<<gemmBlocks, 256, 0, stream>>>(buf1, LDK, LDK / BK, m1w2t, m1b2,
                                           nullptr, nullptr, nullptr, nullptr, buf2, 1);
    k_gemm<<<gemmBlocks, 256, 0, stream>>>(buf2, LDK, LDK / BK, o1t, o1b,
                                           nullptr, nullptr, nullptr, nullptr, buf3, 2);  // t1 = buf3

    // ---- layer 2 ----
    k_agg<<<NN / 4, 256, 0, stream>>>(buf3, rowptr, eidx, eps2, buf1);
    k_gemm<<<gemmBlocks, 256, 0, stream>>>(buf1, LDK, LDK / BK, m2w1t, m2b1,
                                           m2g, m2bb, m2m, m2v, buf2, 0);
    k_gemm<<<gemmBlocks, 256, 0, stream>>>(buf2, LDK, LDK / BK, m2w2t, m2b2,
                                           nullptr, nullptr, nullptr, nullptr, buf1, 1);
    k_gemm<<<gemmBlocks, 256, 0, stream>>>(buf1, LDK, LDK / BK, o2t, o2b,
                                           nullptr, nullptr, nullptr, nullptr, buf2, 2);  // t2 = buf2

    // ---- layer 3 (mlp2 weights again) ----
    k_agg<<<NN / 4, 256, 0, stream>>>(buf2, rowptr, eidx, eps3, buf1);
    k_gemm<<<gemmBlocks, 256, 0, stream>>>(buf1, LDK, LDK / BK, m2w1t, m2b1,
                                           m2g, m2bb, m2m, m2v, buf3, 0);
    k_gemm<<<gemmBlocks, 256, 0, stream>>>(buf3, LDK, LDK / BK, m2w2t, m2b2,
                                           nullptr, nullptr, nullptr, nullptr, buf1, 1);
    k_gemm<<<gemmBlocks, 256, 0, stream>>>(buf1, LDK, LDK / BK, o3t, o3b,
                                           nullptr, nullptr, nullptr, nullptr, buf3, 2);  // t3 = buf3

    // ---- pooling + readout ----
    k_pool<<<NG, 256, 0, stream>>>(buf3, gstart, pooled);
    k_final<<<NG, 256, 0, stream>>>(pooled, ow, ob, out);
}